// Round 5
// baseline (800.559 us; speedup 1.0000x reference)
//
#include <hip/hip_runtime.h>

#define BB 256
#define TT 1024
#define II 128
#define HH 64
#define BT (BB * TT)

typedef _Float16 h2 __attribute__((ext_vector_type(2)));
typedef _Float16 half8 __attribute__((ext_vector_type(8)));
typedef float f32x4 __attribute__((ext_vector_type(4)));
typedef unsigned int uint;
typedef unsigned short ushort;

#define BC(u) __builtin_bit_cast(h2, (uint)(u))
#define MFMA16(a, b, c) __builtin_amdgcn_mfma_f32_16x16x32_f16((a), (b), (c), 0, 0, 0)
#define SIG(v) __builtin_amdgcn_rcpf(1.0f + __expf(-(v)))
#define TNH(v) (1.0f - 2.0f * __builtin_amdgcn_rcpf(1.0f + __expf(2.0f * (v))))

// one barrier per 2 steps, full lgkm drain (R11-verified schedule)
#define BAR() asm volatile("s_waitcnt lgkmcnt(0)\n\ts_barrier" ::: "memory")

__device__ __forceinline__ uint pk2(float a, float b) {
    h2 h; h[0] = (_Float16)a; h[1] = (_Float16)b;
    return __builtin_bit_cast(uint, h);
}

// ============ Kernel B: 4-wave fused recurrence (R14) =======================
// R14: kernel A is DELETED. Its residue (~230us) was invariant under three
// store-path rewrites (R10/R11/R13) -> its cost is existence-bound (dispatch +
// 268MB HBM round trip + staging), not store-amp. The 4th SIMD per CU was
// idle (192 threads); a W-wave now computes xg in-core, one 16-step window
// ahead, via the SAME MFMA tiling (bitwise-identical f16 gate values):
//   Wave 0 (P):  h0(k)   = lstm0(xgb(k), h0(k-1))           [W_hh0 frags]
//   Wave 1 (Q1): z(k-3)  = W_ih1 . h0(k-3)                  [W_ih1 frags]
//   Wave 2 (Q2): h1(k-6) = act(z(k-6) + W_hh1.h1(k-7) + b)  [W_hh1 frags]
//   Wave 3 (W):  xgb window n+1 (16 steps) during window n's 8 pairs
//                (2 tiles/pair = 8 MFMA, hidden under P's ~1000cy pair)
// w_ih0 f16 fragments live in LDS [tile][kc][q][c] (64KB, conflict-free b128
// reads: full wave reads 1KB contiguous). xgb is double-buffered
// [2][16][264] (row pad 264 breaks write-phase bank aliasing); P reads its
// 4 gates as one b64 at [t][4j]. Removes 134MB write + 134MB read of HBM
// and shrinks workspace 160->32MiB.
__global__ __launch_bounds__(256) __attribute__((amdgpu_waves_per_eu(1, 1)))
void lstm2_core(const float* __restrict__ x, const float* __restrict__ w_ih0,
                const float* __restrict__ w_hh0,
                const float* __restrict__ b_ih0, const float* __restrict__ b_hh0,
                const float* __restrict__ w_ih1, const float* __restrict__ w_hh1,
                const float* __restrict__ b_ih1, const float* __restrict__ b_hh1,
                ushort* __restrict__ h1g)
{
    const int bb = blockIdx.x;
    const int w  = threadIdx.x >> 6;
    const int j  = threadIdx.x & 63;
    const int qq = j >> 4, cc = j & 15;
    const int j4 = j * 4;

    __shared__ __align__(16) uint   h0buf[8][32];      // 8-deep, 64 f16 each
    __shared__ __align__(16) uint   h1buf[32];         // Q2-private
    __shared__ __align__(16) float  zbuf[8][64][4];    // 8-deep float4/lane
    __shared__ __align__(16) ushort xgb[2][16][264];   // dbuf gate windows
    __shared__ __align__(16) uint4  wfrag[16][4][4][16]; // w_ih0 B-frags, 64KB

    // ---- one-time stage: w_ih0 -> f16 MFMA B-fragments in LDS ----
    // frag(tile,kc,q,c) = w_ih0[perm(tile*16+c)][kc*32+q*8 .. +7] packed f16,
    // perm(flat) = (flat&3)*64 + (flat>>2)  (=> xgb col 4j+g holds gate g of j)
    {
        #pragma unroll
        for (int t = 0; t < 16; ++t) {
            const int flat = t * 16 + cc;
            const int srcrow = (flat & 3) * 64 + (flat >> 2);
            const float* p = w_ih0 + (size_t)srcrow * II + w * 32 + qq * 8;
            uint4 v;
            v.x = pk2(p[0], p[1]); v.y = pk2(p[2], p[3]);
            v.z = pk2(p[4], p[5]); v.w = pk2(p[6], p[7]);
            wfrag[t][w][qq][cc] = v;
        }
    }
    __syncthreads();

    // ---- recurrent-weight fragments (waves 0..2): 16 tiles x 2 k-halves ----
    uint4 Bf[16][2];
    if (w < 3) {
        const float* Wsel = (w == 0) ? w_hh0 : (w == 1) ? w_ih1 : w_hh1;
        #pragma unroll
        for (int t = 0; t < 16; ++t) {
            const int row = (t & 3) * 64 + (t >> 2) * 16 + cc;
            const float* rp = Wsel + (size_t)row * 64 + qq * 8;
            #pragma unroll
            for (int kh = 0; kh < 2; ++kh) {
                const float* p = rp + kh * 32;
                uint4 v;
                v.x = pk2(p[0], p[1]); v.y = pk2(p[2], p[3]);
                v.z = pk2(p[4], p[5]); v.w = pk2(p[6], p[7]);
                Bf[t][kh] = v;
            }
        }
    }

    float bI = 0.f, bF = 0.f, bG = 0.f, bO = 0.f;
    if (w == 0) {
        bI = b_ih0[j]       + b_hh0[j];
        bF = b_ih0[64 + j]  + b_hh0[64 + j];
        bG = b_ih0[128 + j] + b_hh0[128 + j];
        bO = b_ih0[192 + j] + b_hh0[192 + j];
    } else if (w == 2) {
        bI = b_ih1[j]       + b_hh1[j];
        bF = b_ih1[64 + j]  + b_hh1[64 + j];
        bG = b_ih1[128 + j] + b_hh1[128 + j];
        bO = b_ih1[192 + j] + b_hh1[192 + j];
    }

    float cst = 0.0f;
    const float* xrow = x + (size_t)bb * TT * II;
    ushort* h1b = h1g + (size_t)bb * TT * 64 + j;

    const f32x4 ZR4 = {0.f, 0.f, 0.f, 0.f};
    const int qlo = qq & 1, qhi = qq >> 1;

    half8 af0 = {0,0,0,0,0,0,0,0}, af1 = {0,0,0,0,0,0,0,0};
    f32x4 zr = {0.f, 0.f, 0.f, 0.f};

    // ---- W-wave state: x regs (one window in flight) + A-frags ----
    float4 xr[8];
    half8 wa0 = {0,0,0,0,0,0,0,0}, wa1 = wa0, wa2 = wa0, wa3 = wa0;

// load x for window WND (16 timesteps): lane covers t = WND*16+cc, k = qq*8(+..)
#define XLOAD(WND) if ((WND) < 64) { \
    const float* xp_ = xrow + (size_t)((WND) * 16 + cc) * II + qq * 8; \
    xr[0] = *(const float4*)(xp_ +  0); xr[1] = *(const float4*)(xp_ +  4); \
    xr[2] = *(const float4*)(xp_ + 32); xr[3] = *(const float4*)(xp_ + 36); \
    xr[4] = *(const float4*)(xp_ + 64); xr[5] = *(const float4*)(xp_ + 68); \
    xr[6] = *(const float4*)(xp_ + 96); xr[7] = *(const float4*)(xp_ + 100); }

#define MKAF4() { uint4 u_; \
    u_.x = pk2(xr[0].x, xr[0].y); u_.y = pk2(xr[0].z, xr[0].w); \
    u_.z = pk2(xr[1].x, xr[1].y); u_.w = pk2(xr[1].z, xr[1].w); \
    wa0 = __builtin_bit_cast(half8, u_); \
    u_.x = pk2(xr[2].x, xr[2].y); u_.y = pk2(xr[2].z, xr[2].w); \
    u_.z = pk2(xr[3].x, xr[3].y); u_.w = pk2(xr[3].z, xr[3].w); \
    wa1 = __builtin_bit_cast(half8, u_); \
    u_.x = pk2(xr[4].x, xr[4].y); u_.y = pk2(xr[4].z, xr[4].w); \
    u_.z = pk2(xr[5].x, xr[5].y); u_.w = pk2(xr[5].z, xr[5].w); \
    wa2 = __builtin_bit_cast(half8, u_); \
    u_.x = pk2(xr[6].x, xr[6].y); u_.y = pk2(xr[6].z, xr[6].w); \
    u_.z = pk2(xr[7].x, xr[7].y); u_.w = pk2(xr[7].z, xr[7].w); \
    wa3 = __builtin_bit_cast(half8, u_); }

// one output tile (16 t x 16 colg) of a window; same MFMA chain order as the
// old kernel A (k chunks 0..3 chained) -> bitwise-identical f16 gates.
#define WTILE(TILE, BUF) { \
    f32x4 d_ = ZR4; \
    d_ = MFMA16(wa0, __builtin_bit_cast(half8, wfrag[TILE][0][qq][cc]), d_); \
    d_ = MFMA16(wa1, __builtin_bit_cast(half8, wfrag[TILE][1][qq][cc]), d_); \
    d_ = MFMA16(wa2, __builtin_bit_cast(half8, wfrag[TILE][2][qq][cc]), d_); \
    d_ = MFMA16(wa3, __builtin_bit_cast(half8, wfrag[TILE][3][qq][cc]), d_); \
    _Pragma("unroll") \
    for (int r_ = 0; r_ < 4; ++r_) { \
        _Float16 hv_ = (_Float16)d_[r_]; \
        xgb[BUF][qq * 4 + r_][(TILE) * 16 + cc] = __builtin_bit_cast(ushort, hv_); } }

    // ---- W prologue: produce window 0, start window-1 loads ----
    if (w == 3) {
        XLOAD(0)
        MKAF4()
        #pragma unroll
        for (int t = 0; t < 16; ++t) WTILE(t, 0)
        XLOAD(1)
    }
    __syncthreads();

#define LDAF(SRC) { const char* hb_ = (const char*)(SRC); \
    af0 = *(const half8*)(hb_ + (qq << 4)); \
    af1 = *(const half8*)(hb_ + 64 + (qq << 4)); }

#define GEMV16(SI, SF, SG, SO) { \
    f32x4 D[16]; \
    _Pragma("unroll") \
    for (int t = 0; t < 16; ++t) { \
        f32x4 d_ = MFMA16(af0, __builtin_bit_cast(half8, Bf[t][0]), ZR4); \
        D[t] = MFMA16(af1, __builtin_bit_cast(half8, Bf[t][1]), d_); } \
    { float a_, b_; \
      a_ = qlo ? D[ 4][0] : D[ 0][0]; b_ = qlo ? D[12][0] : D[ 8][0]; SI = qhi ? b_ : a_; \
      a_ = qlo ? D[ 5][0] : D[ 1][0]; b_ = qlo ? D[13][0] : D[ 9][0]; SF = qhi ? b_ : a_; \
      a_ = qlo ? D[ 6][0] : D[ 2][0]; b_ = qlo ? D[14][0] : D[10][0]; SG = qhi ? b_ : a_; \
      a_ = qlo ? D[ 7][0] : D[ 3][0]; b_ = qlo ? D[15][0] : D[11][0]; SO = qhi ? b_ : a_; } }

#define PSTEP(KK) \
    if ((KK) < TT) { \
        const uint2 xcv = *(const uint2*)&xgb[((KK) >> 4) & 1][(KK) & 15][j4]; \
        float si, sf, sg, so; \
        GEMV16(si, sf, sg, so) \
        h2 xlo = BC(xcv.x), xhi = BC(xcv.y); \
        si += bI + (float)xlo[0]; sf += bF + (float)xlo[1]; \
        sg += bG + (float)xhi[0]; so += bO + (float)xhi[1]; \
        float ii = SIG(si), ff = SIG(sf), gg = TNH(sg), oo = SIG(so); \
        cst = fmaf(ff, cst, ii * gg); \
        float hval = oo * TNH(cst); \
        ((_Float16*)&h0buf[(KK) & 7][0])[j] = (_Float16)hval; \
        LDAF(&h0buf[(KK) & 7][0]) \
    }

#define Q1STEP(KK) { const int i_ = (KK); \
    if (i_ >= 3 && i_ < TT + 3) { \
        const int m_ = i_ - 3; \
        float si, sf, sg, so; \
        GEMV16(si, sf, sg, so) \
        f32x4 zv = {si, sf, sg, so}; \
        *(f32x4*)&zbuf[m_ & 7][j][0] = zv; \
    } \
    if (i_ >= 2 && i_ < TT + 2) LDAF(&h0buf[(i_ - 2) & 7][0]) }

#define Q2STEP(KK) { const int i_ = (KK); \
    if (i_ >= 6) { \
        const int m_ = i_ - 6; \
        float si, sf, sg, so; \
        GEMV16(si, sf, sg, so) \
        si += bI + zr[0]; sf += bF + zr[1]; \
        sg += bG + zr[2]; so += bO + zr[3]; \
        float ii = SIG(si), ff = SIG(sf), gg = TNH(sg), oo = SIG(so); \
        cst = fmaf(ff, cst, ii * gg); \
        float hval = oo * TNH(cst); \
        _Float16 hf = (_Float16)hval; \
        ((_Float16*)&h1buf[0])[j] = hf; \
        LDAF(&h1buf[0]) \
        h1b[(size_t)m_ * 64] = __builtin_bit_cast(ushort, hf); \
    } \
    if (i_ >= 5 && i_ < TT + 5) zr = *(const f32x4*)&zbuf[(i_ - 5) & 7][j][0]; }

    for (int k0 = 0; k0 < TT + 6; k0 += 2) {
        if (w == 0) {
            PSTEP(k0)
            PSTEP(k0 + 1)
        } else if (w == 1) {
            Q1STEP(k0)
            Q1STEP(k0 + 1)
        } else if (w == 2) {
            Q2STEP(k0)
            Q2STEP(k0 + 1)
        } else {
            // W: during window n's pairs, produce window n+1 (2 tiles/pair)
            const int s   = (k0 >> 1) & 7;
            const int wnd = (k0 >> 4) + 1;
            if (s == 0) {
                if (wnd < 64) MKAF4()          // x(wnd) loaded 8 pairs ago
                XLOAD(wnd + 1)                 // issue x(wnd+1), deep prefetch
            }
            if (wnd < 64) {
                const int buf = wnd & 1;
                WTILE(2 * s,     buf)
                WTILE(2 * s + 1, buf)
            }
        }
        BAR();
    }
#undef PSTEP
#undef Q1STEP
#undef Q2STEP
#undef GEMV16
#undef LDAF
#undef WTILE
#undef MKAF4
#undef XLOAD
}

// ============ Kernel C: out[bt] = sigmoid(h1g[bt,:] . w_out + b_out) =========
__global__ __launch_bounds__(256)
void head_gemv(const ushort* __restrict__ h1g, const float* __restrict__ w_out,
               const float* __restrict__ b_out, float* __restrict__ outp)
{
    __shared__ float wsh[64];
    const int tid = threadIdx.x;
    if (tid < 64) wsh[tid] = w_out[tid];
    __syncthreads();
    const int bt = blockIdx.x * 256 + tid;
    const uint4* hp = (const uint4*)(h1g + (size_t)bt * 64);
    float s = 0.0f;
    #pragma unroll
    for (int i = 0; i < 8; ++i) {
        uint4 v = hp[i];
        const float* wp = &wsh[8 * i];
        h2 p;
        p = BC(v.x); s = fmaf((float)p[0], wp[0], s); s = fmaf((float)p[1], wp[1], s);
        p = BC(v.y); s = fmaf((float)p[0], wp[2], s); s = fmaf((float)p[1], wp[3], s);
        p = BC(v.z); s = fmaf((float)p[0], wp[4], s); s = fmaf((float)p[1], wp[5], s);
        p = BC(v.w); s = fmaf((float)p[0], wp[6], s); s = fmaf((float)p[1], wp[7], s);
    }
    outp[bt] = __builtin_amdgcn_rcpf(1.0f + __expf(-(s + b_out[0])));
}

extern "C" void kernel_launch(void* const* d_in, const int* in_sizes, int n_in,
                              void* d_out, int out_size, void* d_ws, size_t ws_size,
                              hipStream_t stream) {
    const float* x     = (const float*)d_in[0];
    const float* w_ih0 = (const float*)d_in[1];
    const float* w_hh0 = (const float*)d_in[2];
    const float* b_ih0 = (const float*)d_in[3];
    const float* b_hh0 = (const float*)d_in[4];
    const float* w_ih1 = (const float*)d_in[5];
    const float* w_hh1 = (const float*)d_in[6];
    const float* b_ih1 = (const float*)d_in[7];
    const float* b_hh1 = (const float*)d_in[8];
    const float* w_out = (const float*)d_in[9];
    const float* b_out = (const float*)d_in[10];
    float* out = (float*)d_out;

    ushort* h1g = (ushort*)d_ws;   // 32 MiB (xg workspace eliminated)

    hipLaunchKernelGGL(lstm2_core, dim3(BB), dim3(256), 0, stream,
                       x, w_ih0, w_hh0, b_ih0, b_hh0,
                       w_ih1, w_hh1, b_ih1, b_hh1, h1g);
    hipLaunchKernelGGL(head_gemv, dim3(BT / 256), dim3(256), 0, stream,
                       h1g, w_out, b_out, out);
}